// Round 16
// baseline (1513.047 us; speedup 1.0000x reference)
//
#include <hip/hip_runtime.h>
#include <stdint.h>

#define T_ 128
#define B_ 256
#define D_ 512
#define H_ 768
#define NG 3072   // 4*H
#define OUT_ 60

using bf16x8 = __attribute__((ext_vector_type(8))) __bf16;
using f32x4  = __attribute__((ext_vector_type(4))) float;
using u32x4  = __attribute__((ext_vector_type(4))) unsigned int;

// ---------------- ws layout (bytes) ----------------
#define OFF_XB   ((size_t)0)                        // x bf16 linear [T*B][D]
#define OFF_WI   (OFF_XB + (size_t)T_*B_*D_*2)      // W_ih bf16 linear [NG][D]
#define OFF_WHPK (OFF_WI + (size_t)NG*D_*2)         // W_hh frag-packed per strip
#define OFF_H    (OFF_WHPK + (size_t)NG*H_*2)       // h dbuf [2][16g][16][768] bf16
#define OFF_HT   (OFF_H + (size_t)2*B_*H_*2)        // final h f32
#define OFF_BAR  (OFF_HT + (size_t)B_*H_*4)         // flags/probe, 64KB
#define OFF_XP   (OFF_BAR + 65536)                  // xp row-major [T*B][NG] bf16, 201MB
#define OFF_END  (OFF_XP + (size_t)T_*B_*NG*2)
// bar[] u32 map: flags [(g*32+s)*16], g in 0..15 -> [0,8192) — sc1 ONLY;
// xcc publish [8192+blk]; init ctr [8704]

__device__ __forceinline__ unsigned short f2bf(float f) {
  union { float f; unsigned u; } v; v.f = f;
  unsigned r = (v.u + 0x7fffu + ((v.u >> 16) & 1u)) >> 16;  // RNE
  return (unsigned short)r;
}
__device__ __forceinline__ float sigf(float x) {
  return __builtin_amdgcn_rcpf(1.0f + __expf(-x));
}
__device__ __forceinline__ float tanhf_(float x) {
  return 2.0f * __builtin_amdgcn_rcpf(1.0f + __expf(-2.0f * x)) - 1.0f;
}
__device__ __forceinline__ void gload16(const void* g, void* l) {
  __builtin_amdgcn_global_load_lds(
      (const __attribute__((address_space(1))) unsigned int*)g,
      (__attribute__((address_space(3))) unsigned int*)l, 16, 0, 0);
}
template<int OFF, bool SC1>
__device__ __forceinline__ u32x4 ld16(const void* p) {
  u32x4 r;
  if constexpr (SC1)
    asm volatile("global_load_dwordx4 %0, %1, off offset:%c2 sc0 sc1"
                 : "=v"(r) : "v"(p), "i"(OFF) : "memory");
  else
    asm volatile("global_load_dwordx4 %0, %1, off offset:%c2 sc0"
                 : "=v"(r) : "v"(p), "i"(OFF) : "memory");
  return r;
}
__device__ __forceinline__ unsigned ld4coh(const unsigned* p) {  // sc1 poll (+wait)
  unsigned r;
  asm volatile("global_load_dword %0, %1, off sc0 sc1\n\ts_waitcnt vmcnt(0)"
               : "=v"(r) : "v"(p) : "memory");
  return r;
}
template<bool SC1>
__device__ __forceinline__ void st2(ushort* p, unsigned v) {
  if constexpr (SC1)
    asm volatile("global_store_short %0, %1, off sc0 sc1" :: "v"(p), "v"(v) : "memory");
  else
    asm volatile("global_store_short %0, %1, off sc0" :: "v"(p), "v"(v) : "memory");
}
__device__ __forceinline__ void st4coh(unsigned* p, unsigned v) {
  asm volatile("global_store_dword %0, %1, off sc0 sc1" :: "v"(p), "v"(v) : "memory");
}

// ---------------- phase A: convert + pack + init ----------------
__global__ void prep_kernel(const float* __restrict__ x,
                            const float* __restrict__ wihf,
                            const float* __restrict__ whhf,
                            uint8_t* __restrict__ ws) {
  ushort* xb = (ushort*)(ws + OFF_XB);
  ushort* wi = (ushort*)(ws + OFF_WI);
  ushort* whpk = (ushort*)(ws + OFF_WHPK);
  unsigned* bar = (unsigned*)(ws + OFF_BAR);
  const size_t tid = (size_t)blockIdx.x * blockDim.x + threadIdx.x;
  const size_t nth = (size_t)gridDim.x * blockDim.x;

  for (size_t i = tid; i < (size_t)T_*B_*D_/4; i += nth) {
    float4 v = ((const float4*)x)[i];
    ushort4 o; o.x=f2bf(v.x); o.y=f2bf(v.y); o.z=f2bf(v.z); o.w=f2bf(v.w);
    ((ushort4*)xb)[i] = o;
  }
  for (size_t i = tid; i < (size_t)NG*D_/4; i += nth) {
    float4 v = ((const float4*)wihf)[i];
    ushort4 o; o.x=f2bf(v.x); o.y=f2bf(v.y); o.z=f2bf(v.z); o.w=f2bf(v.w);
    ((ushort4*)wi)[i] = o;
  }
  // W_hh -> frag-packed per strip: chunk ((s*24+kf)*6+nt)*64+L  (verified R5)
  for (size_t c = tid; c < (size_t)294912; c += nth) {
    const unsigned L = (unsigned)c & 63u;
    const unsigned r1 = (unsigned)(c >> 6);
    const unsigned nt = r1 % 6u, r2 = r1 / 6u;
    const unsigned kf = r2 % 24u, s = r2 / 24u;
    const unsigned i = nt*16u + (L & 15u);
    const unsigned G = (i & 3u)*768u + s*24u + (i >> 2);
    const unsigned k0 = kf*32u + (L >> 4)*8u;
    const float4 v0 = *(const float4*)(whhf + (size_t)G*768u + k0);
    const float4 v1 = *(const float4*)(whhf + (size_t)G*768u + k0 + 4);
    ushort4 o0, o1;
    o0.x=f2bf(v0.x); o0.y=f2bf(v0.y); o0.z=f2bf(v0.z); o0.w=f2bf(v0.w);
    o1.x=f2bf(v1.x); o1.y=f2bf(v1.y); o1.z=f2bf(v1.z); o1.w=f2bf(v1.w);
    *(ushort4*)(whpk + c*8)     = o0;
    *(ushort4*)(whpk + c*8 + 4) = o1;
  }
  // zero flag/probe region THROUGH the coherence point (replay-safe)
  for (size_t i = tid; i < 16384; i += nth) st4coh(&bar[i], 0u);
}

// ---------------- phase B: xp = x @ W_ih^T (128x128 tile, BK=64; verified R2) ----------------
__global__ __launch_bounds__(256) void xproj_kernel(uint8_t* __restrict__ ws) {
  const ushort* __restrict__ xb = (const ushort*)(ws + OFF_XB);
  const ushort* __restrict__ wi = (const ushort*)(ws + OFF_WI);
  ushort* __restrict__ xp = (ushort*)(ws + OFF_XP);

  __shared__ ushort smA[128*64];
  __shared__ ushort smB[128*64];

  const int tid = threadIdx.x;
  const int lane = tid & 63;
  const int w = tid >> 6;
  const int bn = blockIdx.x % 24;
  const int bm = blockIdx.x / 24;
  const int m0 = bm * 128, n0 = bn * 128;
  const int mi = (w >> 1) * 64, ni = (w & 1) * 64;

  f32x4 acc[4][4] = {};

  for (int k0 = 0; k0 < D_; k0 += 64) {
    __syncthreads();
    #pragma unroll
    for (int i = 0; i < 4; ++i) {
      const int ig = w*4 + i;
      const int o  = ig*1024 + lane*16;
      const int row = o >> 7;
      const int colB = o & 127;
      const int scol = colB ^ ((row & 7) << 4);
      gload16((const uint8_t*)xb + ((size_t)(m0+row)*D_ + k0)*2 + scol,
              (uint8_t*)smA + ig*1024);
      gload16((const uint8_t*)wi + ((size_t)(n0+row)*D_ + k0)*2 + scol,
              (uint8_t*)smB + ig*1024);
    }
    __syncthreads();
    #pragma unroll
    for (int kk = 0; kk < 2; ++kk) {
      const int colB = kk*64 + (lane >> 4)*16;
      bf16x8 a[4], b[4];
      #pragma unroll
      for (int mt = 0; mt < 4; ++mt) {
        const int row = mi + mt*16 + (lane & 15);
        a[mt] = *(const bf16x8*)((const uint8_t*)smA + row*128 + (colB ^ ((row & 7) << 4)));
      }
      #pragma unroll
      for (int nt = 0; nt < 4; ++nt) {
        const int row = ni + nt*16 + (lane & 15);
        b[nt] = *(const bf16x8*)((const uint8_t*)smB + row*128 + (colB ^ ((row & 7) << 4)));
      }
      #pragma unroll
      for (int mt = 0; mt < 4; ++mt)
        #pragma unroll
        for (int nt = 0; nt < 4; ++nt)
          acc[mt][nt] = __builtin_amdgcn_mfma_f32_16x16x32_bf16(a[mt], b[nt], acc[mt][nt], 0, 0, 0);
    }
  }
  #pragma unroll
  for (int mt = 0; mt < 4; ++mt)
    #pragma unroll
    for (int nt = 0; nt < 4; ++nt) {
      const int r0 = m0 + mi + mt*16 + (lane >> 4)*4;
      const int c  = n0 + ni + nt*16 + (lane & 15);
      #pragma unroll
      for (int r = 0; r < 4; ++r)
        xp[(size_t)(r0 + r)*NG + c] = f2bf(acc[mt][nt][r]);
    }
}

// ---------------- phase C: persistent recurrence, 2-stream interleave ----------------
// 256 WGs, 1/CU. XCD x = blk&7 hosts groups {2x, 2x+1} (16 rows each); s = blk>>3
// = 24-col strip. Each WG alternates stream A (group 2x) and B (group 2x+1) in
// program order: A's flag post->detect latency hides under B's compute slot.
// Flags: sc1 post + sc1 poll per group (R7-proven). W_hh strip LDS shared by both.
template<bool SC1>
__device__ __forceinline__ void stream_slot(
    uint8_t* __restrict__ ws, const ushort* __restrict__ whh_lds, float* gw,
    unsigned* __restrict__ bar, int t, int g, int s,
    int tid, int lane, int l15, int hi,
    int nt0, int nt1, bool s1store,
    const float bias[2][4], const int colj[2],
    ushort xq[8], float cc[2])
{
  ushort* hb = (ushort*)(ws + OFF_H);
  const ushort* xp = (const ushort*)(ws + OFF_XP);
  float* hT = (float*)(ws + OFF_HT);

  f32x4 acc0 = {0.f,0.f,0.f,0.f}, acc1 = {0.f,0.f,0.f,0.f};
  if (t > 0) {
    // all-waves poll: all 32 strips of group g posted h(t)
    const int pl = (lane < 32) ? lane : 31;
    const unsigned* fp = bar + (size_t)(g*32 + pl) * 16;
    while (1) {
      const unsigned v = ld4coh(fp);
      if (__all((int)(v >= (unsigned)t))) break;
      __builtin_amdgcn_s_sleep(1);
    }
    // h A-frags: 16 rows of group g, 24 x 16B (L2-local in intra-XCD mode)
    const ushort* hr = hb + ((size_t)(t & 1)*16 + g)*((size_t)16*H_)
                       + (size_t)l15*H_ + hi*8;
    u32x4 ah[24];
    #define LH(i) ah[i] = ld16<(i)*64, SC1>(hr)
    LH(0); LH(1); LH(2); LH(3); LH(4); LH(5); LH(6); LH(7);
    LH(8); LH(9); LH(10); LH(11); LH(12); LH(13); LH(14); LH(15);
    LH(16); LH(17); LH(18); LH(19); LH(20); LH(21); LH(22); LH(23);
    #undef LH
    asm volatile("s_waitcnt vmcnt(0)" ::: "memory");
    __builtin_amdgcn_sched_barrier(0);
    #pragma unroll
    for (int kf = 0; kf < 24; ++kf) {
      const bf16x8 a = *(const bf16x8*)&ah[kf];
      const bf16x8 b0 = *(const bf16x8*)(whh_lds + (size_t)((kf*6 + nt0)*64 + lane)*8);
      acc0 = __builtin_amdgcn_mfma_f32_16x16x32_bf16(a, b0, acc0, 0, 0, 0);
      const bf16x8 b1 = *(const bf16x8*)(whh_lds + (size_t)((kf*6 + nt1)*64 + lane)*8);
      acc1 = __builtin_amdgcn_mfma_f32_16x16x32_bf16(a, b1, acc1, 0, 0, 0);
    }
  }
  // gate xpose (wave-local LDS region, no barrier) + activations (+ xp + bias)
  #pragma unroll
  for (int r = 0; r < 4; ++r) {
    gw[(size_t)l15*17 + hi*4 + r] = acc0[r];
    gw[(size_t)(16 + l15)*17 + hi*4 + r] = acc1[r];
  }
  float hv[2];
  #pragma unroll
  for (int jj = 0; jj < 2; ++jj) {
    float gq[4];
    #pragma unroll
    for (int q = 0; q < 4; ++q) {
      union { unsigned u; float f; } xv; xv.u = ((unsigned)xq[jj*4 + q]) << 16;
      gq[q] = gw[(size_t)(jj*16 + hi*4 + q)*17 + l15] + xv.f + bias[jj][q];
    }
    const float iv = sigf(gq[0]);
    const float fv = sigf(gq[1]);
    const float gv = tanhf_(gq[2]);
    const float ov = sigf(gq[3]);
    const float cn = fv*cc[jj] + iv*gv;
    cc[jj] = cn;
    hv[jj] = ov * tanhf_(cn);
  }
  if (t == T_-1) {
    hT[(size_t)(g*16 + l15)*H_ + colj[0]] = hv[0];
    if (s1store) hT[(size_t)(g*16 + l15)*H_ + colj[1]] = hv[1];
    return;
  }
  // direct 2B h-stores (R7-proven)
  ushort* hn = hb + ((size_t)((t+1) & 1)*16 + g)*((size_t)16*H_);
  st2<SC1>(hn + (size_t)l15*H_ + colj[0], (unsigned)f2bf(hv[0]));
  if (s1store) st2<SC1>(hn + (size_t)l15*H_ + colj[1], (unsigned)f2bf(hv[1]));
  asm volatile("s_waitcnt vmcnt(0)" ::: "memory");   // this wave's stores done
  __syncthreads();                                    // all waves' stores done
  if (tid == 0) st4coh(bar + (size_t)(g*32 + s)*16, (unsigned)(t + 1));
  {  // prefetch xq(t+1) in the post-flag slack (plain loads)
    const ushort* p = xp + ((size_t)(t + 1)*B_ + g*16 + l15)*NG;
    #pragma unroll
    for (int jj = 0; jj < 2; ++jj)
      #pragma unroll
      for (int q = 0; q < 4; ++q)
        xq[jj*4 + q] = p[q*H_ + colj[jj]];
  }
}

template<bool SC1>
__device__ __forceinline__ void run_loop(uint8_t* ws, const ushort* whh_lds, float* gbuf,
                                         const float* bih, const float* bhh,
                                         int tid, int x, int s) {
  const int lane = tid & 63, w = tid >> 6;
  const int l15 = lane & 15, hi = lane >> 4;
  unsigned* bar = (unsigned*)(ws + OFF_BAR);
  const ushort* xp = (const ushort*)(ws + OFF_XP);
  float* gw = gbuf + w*544;   // per-wave 2x16 N-pos x 16 M (stride 17)

  // n-tile assignment: waves 0,1 own {w, w+4}; waves 2,3 duplicate {w}
  const int nt0 = w;
  const int nt1 = (w < 2) ? (w + 4) : w;
  const bool s1store = (w < 2);
  const int colj[2] = { s*24 + nt0*4 + hi, s*24 + nt1*4 + hi };

  float bias[2][4];   // shared by both streams (same cols)
  #pragma unroll
  for (int jj = 0; jj < 2; ++jj)
    #pragma unroll
    for (int q = 0; q < 4; ++q)
      bias[jj][q] = bih[q*H_ + colj[jj]] + bhh[q*H_ + colj[jj]];

  const int gA = x*2, gB = x*2 + 1;
  ushort xqA[8], xqB[8];
  float ccA[2] = {0.f, 0.f}, ccB[2] = {0.f, 0.f};
  {  // prefetch xp(0) for both streams
    const ushort* pA = xp + ((size_t)gA*16 + l15)*NG;
    const ushort* pB = xp + ((size_t)gB*16 + l15)*NG;
    #pragma unroll
    for (int jj = 0; jj < 2; ++jj)
      #pragma unroll
      for (int q = 0; q < 4; ++q) {
        xqA[jj*4 + q] = pA[q*H_ + colj[jj]];
        xqB[jj*4 + q] = pB[q*H_ + colj[jj]];
      }
  }

  #pragma unroll 1
  for (int t = 0; t < T_; ++t) {
    stream_slot<SC1>(ws, whh_lds, gw, bar, t, gA, s, tid, lane, l15, hi,
                     nt0, nt1, s1store, bias, colj, xqA, ccA);
    stream_slot<SC1>(ws, whh_lds, gw, bar, t, gB, s, tid, lane, l15, hi,
                     nt0, nt1, s1store, bias, colj, xqB, ccB);
  }
}

__global__ __launch_bounds__(256, 1) void lstm_kernel(uint8_t* __restrict__ ws,
                                                      const float* __restrict__ bih,
                                                      const float* __restrict__ bhh) {
  __shared__ ushort whh_lds[73728];   // 144 KB: [kf 24][nt 6][64] 16B frag chunks
  __shared__ float gbuf[2176];        // 8.5 KB: 4 waves x 2 tiles x 16x17
  const int tid = threadIdx.x, lane = tid & 63, w = tid >> 6;
  const int x = blockIdx.x & 7, s = blockIdx.x >> 3;
  unsigned* bar = (unsigned*)(ws + OFF_BAR);

  const uint8_t* wsrc = ws + OFF_WHPK + (size_t)s*9216*16;
  #pragma unroll
  for (int i = 0; i < 36; ++i) {
    const int cb = (w*36 + i)*64;
    gload16(wsrc + (size_t)(cb + lane)*16, (uint8_t*)whh_lds + (size_t)cb*16);
  }

  // publish XCC_ID (sc1); one-time global init barrier (system atomic)
  const unsigned xcd = __builtin_amdgcn_s_getreg((3 << 11) | 20) & 7u;  // HW_REG_XCC_ID
  if (tid == 0) {
    st4coh(bar + 8192 + blockIdx.x, xcd);
    asm volatile("s_waitcnt vmcnt(0)" ::: "memory");
    __hip_atomic_fetch_add(bar + 8704, 1u, __ATOMIC_RELAXED, __HIP_MEMORY_SCOPE_SYSTEM);
    while (__hip_atomic_load(bar + 8704, __ATOMIC_RELAXED, __HIP_MEMORY_SCOPE_SYSTEM) < 256u)
      __builtin_amdgcn_s_sleep(2);
  }
  __syncthreads();
  const int pl = (lane < 32) ? lane : 31;
  const unsigned oxcc = ld4coh(bar + 8192 + x + 8*pl);   // the 32 WGs of my XCD
  const bool local = __all((int)(oxcc == xcd));

  asm volatile("s_waitcnt vmcnt(0) lgkmcnt(0)" ::: "memory");
  __syncthreads();                                 // whh_lds fully staged

  if (local) run_loop<false>(ws, whh_lds, gbuf, bih, bhh, tid, x, s);
  else       run_loop<true >(ws, whh_lds, gbuf, bih, bhh, tid, x, s);
}

// ---------------- phase D: out = h_T @ W_fc^T + b_fc ----------------
__global__ __launch_bounds__(64) void fc_kernel(const uint8_t* __restrict__ ws,
                                                const float* __restrict__ wfc,
                                                const float* __restrict__ bfc,
                                                float* __restrict__ out) {
  const float* hT = (const float*)(ws + OFF_HT);
  const int b = blockIdx.x;
  const int lane = threadIdx.x;
  const float* hr = hT + (size_t)b*H_;
  float hv[12];
  #pragma unroll
  for (int i = 0; i < 12; ++i) hv[i] = hr[lane + i*64];
  for (int o = 0; o < OUT_; ++o) {
    const float* wr = wfc + (size_t)o*H_;
    float sum = 0.f;
    #pragma unroll
    for (int i = 0; i < 12; ++i) sum += hv[i] * wr[lane + i*64];
    #pragma unroll
    for (int off = 32; off; off >>= 1) sum += __shfl_xor(sum, off);
    if (lane == 0) out[(size_t)b*OUT_ + o] = sum + bfc[o];
  }
}

extern "C" void kernel_launch(void* const* d_in, const int* in_sizes, int n_in,
                              void* d_out, int out_size, void* d_ws, size_t ws_size,
                              hipStream_t stream) {
  const float* x   = (const float*)d_in[0];
  const float* wih = (const float*)d_in[1];
  const float* whh = (const float*)d_in[2];
  const float* bih = (const float*)d_in[3];
  const float* bhh = (const float*)d_in[4];
  const float* wfc = (const float*)d_in[5];
  const float* bfc = (const float*)d_in[6];
  uint8_t* ws = (uint8_t*)d_ws;
  float* out = (float*)d_out;

  prep_kernel<<<dim3(2048), dim3(256), 0, stream>>>(x, wih, whh, ws);
  xproj_kernel<<<dim3(256*24), dim3(256), 0, stream>>>(ws);
  lstm_kernel<<<dim3(256), dim3(256), 0, stream>>>(ws, bih, bhh);
  fc_kernel<<<dim3(256), dim3(64), 0, stream>>>(ws, wfc, bfc, out);
}

// Round 17
// 991.085 us; speedup vs baseline: 1.5267x; 1.5267x over previous
//
#include <hip/hip_runtime.h>
#include <stdint.h>

#define T_ 128
#define B_ 256
#define D_ 512
#define H_ 768
#define NG 3072   // 4*H
#define OUT_ 60

using bf16x8 = __attribute__((ext_vector_type(8))) __bf16;
using f32x4  = __attribute__((ext_vector_type(4))) float;
using u32x4  = __attribute__((ext_vector_type(4))) unsigned int;

// ---------------- ws layout (bytes) ----------------
#define OFF_XB   ((size_t)0)                        // x bf16 linear [T*B][D]
#define OFF_WI   (OFF_XB + (size_t)T_*B_*D_*2)      // W_ih bf16 linear [NG][D]
#define OFF_WHPK (OFF_WI + (size_t)NG*D_*2)         // W_hh frag-packed per strip
#define OFF_H    (OFF_WHPK + (size_t)NG*H_*2)       // h dbuf [2][8g][32][768] bf16
#define OFF_HT   (OFF_H + (size_t)2*B_*H_*2)        // final h f32
#define OFF_BAR  (OFF_HT + (size_t)B_*H_*4)         // flags/probe, 64KB
#define OFF_XP   (OFF_BAR + 65536)                  // xp row-major [T*B][NG] bf16, 201MB
#define OFF_END  (OFF_XP + (size_t)T_*B_*NG*2)
// bar[] u32 map: flags PACKED [g*32+s] in [0,256) — one 128B line per group,
// sc1 ONLY (R7-proven semantics; packing = anti poll-storm);
// xcc publish [4096+blk]; init ctr [5120]

__device__ __forceinline__ unsigned short f2bf(float f) {
  union { float f; unsigned u; } v; v.f = f;
  unsigned r = (v.u + 0x7fffu + ((v.u >> 16) & 1u)) >> 16;  // RNE
  return (unsigned short)r;
}
__device__ __forceinline__ float sigf(float x) {
  return __builtin_amdgcn_rcpf(1.0f + __expf(-x));
}
__device__ __forceinline__ float tanhf_(float x) {
  return 2.0f * __builtin_amdgcn_rcpf(1.0f + __expf(-2.0f * x)) - 1.0f;
}
__device__ __forceinline__ void gload16(const void* g, void* l) {
  __builtin_amdgcn_global_load_lds(
      (const __attribute__((address_space(1))) unsigned int*)g,
      (__attribute__((address_space(3))) unsigned int*)l, 16, 0, 0);
}
template<int OFF, bool SC1>
__device__ __forceinline__ u32x4 ld16(const void* p) {
  u32x4 r;
  if constexpr (SC1)
    asm volatile("global_load_dwordx4 %0, %1, off offset:%c2 sc0 sc1"
                 : "=v"(r) : "v"(p), "i"(OFF) : "memory");
  else
    asm volatile("global_load_dwordx4 %0, %1, off offset:%c2 sc0"
                 : "=v"(r) : "v"(p), "i"(OFF) : "memory");
  return r;
}
__device__ __forceinline__ unsigned ld4coh(const unsigned* p) {  // sc1 poll (+wait)
  unsigned r;
  asm volatile("global_load_dword %0, %1, off sc0 sc1\n\ts_waitcnt vmcnt(0)"
               : "=v"(r) : "v"(p) : "memory");
  return r;
}
template<bool SC1>
__device__ __forceinline__ void st2(ushort* p, unsigned v) {
  if constexpr (SC1)
    asm volatile("global_store_short %0, %1, off sc0 sc1" :: "v"(p), "v"(v) : "memory");
  else
    asm volatile("global_store_short %0, %1, off sc0" :: "v"(p), "v"(v) : "memory");
}
__device__ __forceinline__ void st4coh(unsigned* p, unsigned v) {
  asm volatile("global_store_dword %0, %1, off sc0 sc1" :: "v"(p), "v"(v) : "memory");
}

// ---------------- phase A: convert + pack + init ----------------
__global__ void prep_kernel(const float* __restrict__ x,
                            const float* __restrict__ wihf,
                            const float* __restrict__ whhf,
                            uint8_t* __restrict__ ws) {
  ushort* xb = (ushort*)(ws + OFF_XB);
  ushort* wi = (ushort*)(ws + OFF_WI);
  ushort* whpk = (ushort*)(ws + OFF_WHPK);
  unsigned* bar = (unsigned*)(ws + OFF_BAR);
  const size_t tid = (size_t)blockIdx.x * blockDim.x + threadIdx.x;
  const size_t nth = (size_t)gridDim.x * blockDim.x;

  for (size_t i = tid; i < (size_t)T_*B_*D_/4; i += nth) {
    float4 v = ((const float4*)x)[i];
    ushort4 o; o.x=f2bf(v.x); o.y=f2bf(v.y); o.z=f2bf(v.z); o.w=f2bf(v.w);
    ((ushort4*)xb)[i] = o;
  }
  for (size_t i = tid; i < (size_t)NG*D_/4; i += nth) {
    float4 v = ((const float4*)wihf)[i];
    ushort4 o; o.x=f2bf(v.x); o.y=f2bf(v.y); o.z=f2bf(v.z); o.w=f2bf(v.w);
    ((ushort4*)wi)[i] = o;
  }
  // W_hh -> frag-packed per strip: chunk ((s*24+kf)*6+nt)*64+L  (verified R5)
  for (size_t c = tid; c < (size_t)294912; c += nth) {
    const unsigned L = (unsigned)c & 63u;
    const unsigned r1 = (unsigned)(c >> 6);
    const unsigned nt = r1 % 6u, r2 = r1 / 6u;
    const unsigned kf = r2 % 24u, s = r2 / 24u;
    const unsigned i = nt*16u + (L & 15u);
    const unsigned G = (i & 3u)*768u + s*24u + (i >> 2);
    const unsigned k0 = kf*32u + (L >> 4)*8u;
    const float4 v0 = *(const float4*)(whhf + (size_t)G*768u + k0);
    const float4 v1 = *(const float4*)(whhf + (size_t)G*768u + k0 + 4);
    ushort4 o0, o1;
    o0.x=f2bf(v0.x); o0.y=f2bf(v0.y); o0.z=f2bf(v0.z); o0.w=f2bf(v0.w);
    o1.x=f2bf(v1.x); o1.y=f2bf(v1.y); o1.z=f2bf(v1.z); o1.w=f2bf(v1.w);
    *(ushort4*)(whpk + c*8)     = o0;
    *(ushort4*)(whpk + c*8 + 4) = o1;
  }
  // zero flag/probe region THROUGH the coherence point (replay-safe)
  for (size_t i = tid; i < 16384; i += nth) st4coh(&bar[i], 0u);
}

// ---------------- phase B: xp = x @ W_ih^T (128x128 tile, BK=64; verified R2) ----------------
__global__ __launch_bounds__(256) void xproj_kernel(uint8_t* __restrict__ ws) {
  const ushort* __restrict__ xb = (const ushort*)(ws + OFF_XB);
  const ushort* __restrict__ wi = (const ushort*)(ws + OFF_WI);
  ushort* __restrict__ xp = (ushort*)(ws + OFF_XP);

  __shared__ ushort smA[128*64];
  __shared__ ushort smB[128*64];

  const int tid = threadIdx.x;
  const int lane = tid & 63;
  const int w = tid >> 6;
  const int bn = blockIdx.x % 24;
  const int bm = blockIdx.x / 24;
  const int m0 = bm * 128, n0 = bn * 128;
  const int mi = (w >> 1) * 64, ni = (w & 1) * 64;

  f32x4 acc[4][4] = {};

  for (int k0 = 0; k0 < D_; k0 += 64) {
    __syncthreads();
    #pragma unroll
    for (int i = 0; i < 4; ++i) {
      const int ig = w*4 + i;
      const int o  = ig*1024 + lane*16;
      const int row = o >> 7;
      const int colB = o & 127;
      const int scol = colB ^ ((row & 7) << 4);
      gload16((const uint8_t*)xb + ((size_t)(m0+row)*D_ + k0)*2 + scol,
              (uint8_t*)smA + ig*1024);
      gload16((const uint8_t*)wi + ((size_t)(n0+row)*D_ + k0)*2 + scol,
              (uint8_t*)smB + ig*1024);
    }
    __syncthreads();
    #pragma unroll
    for (int kk = 0; kk < 2; ++kk) {
      const int colB = kk*64 + (lane >> 4)*16;
      bf16x8 a[4], b[4];
      #pragma unroll
      for (int mt = 0; mt < 4; ++mt) {
        const int row = mi + mt*16 + (lane & 15);
        a[mt] = *(const bf16x8*)((const uint8_t*)smA + row*128 + (colB ^ ((row & 7) << 4)));
      }
      #pragma unroll
      for (int nt = 0; nt < 4; ++nt) {
        const int row = ni + nt*16 + (lane & 15);
        b[nt] = *(const bf16x8*)((const uint8_t*)smB + row*128 + (colB ^ ((row & 7) << 4)));
      }
      #pragma unroll
      for (int mt = 0; mt < 4; ++mt)
        #pragma unroll
        for (int nt = 0; nt < 4; ++nt)
          acc[mt][nt] = __builtin_amdgcn_mfma_f32_16x16x32_bf16(a[mt], b[nt], acc[mt][nt], 0, 0, 0);
    }
  }
  #pragma unroll
  for (int mt = 0; mt < 4; ++mt)
    #pragma unroll
    for (int nt = 0; nt < 4; ++nt) {
      const int r0 = m0 + mi + mt*16 + (lane >> 4)*4;
      const int c  = n0 + ni + nt*16 + (lane & 15);
      #pragma unroll
      for (int r = 0; r < 4; ++r)
        xp[(size_t)(r0 + r)*NG + c] = f2bf(acc[mt][nt][r]);
    }
}

// ---------------- phase C: persistent recurrence (R15 structure, PACKED flags) ----------------
// 256 WGs, 1/CU. 8 groups x 32 strips. Flags: sc1 post + sc1 poll, but all 32
// group flags in ONE 128B line -> a wave's poll = 1 coalesced line read
// (vs 32 line reads at 64B padding) -> kills the L3 poll request storm.
template<bool SC1>
__device__ __forceinline__ void run_loop(uint8_t* ws, const ushort* whh_lds, float* gbuf,
                                         const float* bih, const float* bhh,
                                         int tid, int g, int s) {
  const int lane = tid & 63, w = tid >> 6, wq = w & 1, wm = w >> 1;
  const int l15 = lane & 15, hi = lane >> 4;
  ushort* hb = (ushort*)(ws + OFF_H);
  const ushort* xp = (const ushort*)(ws + OFF_XP);
  float* hT = (float*)(ws + OFF_HT);
  unsigned* bar = (unsigned*)(ws + OFF_BAR);
  float* gw = gbuf + w*816;

  float bias[3][4];
  #pragma unroll
  for (int j = 0; j < 3; ++j) {
    const int col = s*24 + wq*12 + hi + 4*j;
    #pragma unroll
    for (int q = 0; q < 4; ++q) bias[j][q] = bih[q*H_ + col] + bhh[q*H_ + col];
  }
  const int pl = (lane < 32) ? lane : 31;
  const unsigned* fp = bar + (size_t)(g*32 + pl);   // PACKED: coalesced line poll

  // per-thread xp source: row = g*32+wm*16+l15, cols q*768 + s*24+wq*12+hi (+4j)
  const ushort* xpb = xp + (size_t)(g*32 + wm*16 + l15)*NG + s*24 + wq*12 + hi;
  ushort xq[12];   // [q][j], plain loads (compiler-managed waitcnt)
  {
    const ushort* p = xpb;
    #pragma unroll
    for (int q = 0; q < 4; ++q)
      #pragma unroll
      for (int j = 0; j < 3; ++j)
        xq[q*3+j] = p[q*768 + 4*j];
  }

  float cc[3] = {0.f, 0.f, 0.f};

  #pragma unroll 1
  for (int t = 0; t < T_; ++t) {
    f32x4 acc[3] = {};
    if (t > 0) {
      // all waves poll independently; one coalesced line read per iteration
      while (1) {
        const unsigned v = ld4coh(fp);
        if (__all((int)(v >= (unsigned)t))) break;
        __builtin_amdgcn_s_sleep(1);
      }
      // h A-frags: 24 x 16B loads (L2-local in intra-XCD mode)
      const ushort* hr = hb + ((size_t)(t & 1)*8 + g)*((size_t)32*H_)
                         + (size_t)(wm*16 + l15)*H_ + hi*8;
      u32x4 ah[24];
      #define LH(i) ah[i] = ld16<(i)*64, SC1>(hr)
      LH(0); LH(1); LH(2); LH(3); LH(4); LH(5); LH(6); LH(7);
      LH(8); LH(9); LH(10); LH(11); LH(12); LH(13); LH(14); LH(15);
      LH(16); LH(17); LH(18); LH(19); LH(20); LH(21); LH(22); LH(23);
      #undef LH
      asm volatile("s_waitcnt vmcnt(0)" ::: "memory");
      __builtin_amdgcn_sched_barrier(0);
      #pragma unroll
      for (int kf = 0; kf < 24; ++kf) {
        const bf16x8 a = *(const bf16x8*)&ah[kf];
        #pragma unroll
        for (int n = 0; n < 3; ++n) {
          const bf16x8 b = *(const bf16x8*)(whh_lds + (size_t)((kf*6 + wq*3 + n)*64 + lane)*8);
          acc[n] = __builtin_amdgcn_mfma_f32_16x16x32_bf16(a, b, acc[n], 0, 0, 0);
        }
      }
    }
    // gate xpose (wave-local LDS region, no barrier) + activations (+ xp + bias)
    #pragma unroll
    for (int n = 0; n < 3; ++n)
      #pragma unroll
      for (int r = 0; r < 4; ++r)
        gw[(n*16 + l15)*17 + hi*4 + r] = acc[n][r];
    float hv[3];
    #pragma unroll
    for (int j = 0; j < 3; ++j) {
      const int cl = hi + 4*j;
      float gq[4];
      #pragma unroll
      for (int q = 0; q < 4; ++q) {
        union { unsigned u; float f; } xv; xv.u = ((unsigned)xq[q*3 + j]) << 16;
        gq[q] = gw[(cl*4+q)*17 + l15] + xv.f + bias[j][q];
      }
      const float iv = sigf(gq[0]);
      const float fv = sigf(gq[1]);
      const float gv = tanhf_(gq[2]);
      const float ov = sigf(gq[3]);
      const float cn = fv*cc[j] + iv*gv;
      cc[j] = cn;
      hv[j] = ov * tanhf_(cn);
    }
    const int rowl = wm*16 + l15;
    if (t == T_-1) {
      #pragma unroll
      for (int j = 0; j < 3; ++j) {
        const int col = s*24 + wq*12 + hi + 4*j;
        hT[(size_t)(g*32 + rowl)*H_ + col] = hv[j];
      }
      break;
    }
    // direct 2B h-stores (R7-proven)
    ushort* hn = hb + ((size_t)((t+1) & 1)*8 + g)*((size_t)32*H_);
    #pragma unroll
    for (int j = 0; j < 3; ++j) {
      const int col = s*24 + wq*12 + hi + 4*j;
      st2<SC1>(hn + (size_t)rowl*H_ + col, (unsigned)f2bf(hv[j]));
    }
    asm volatile("s_waitcnt vmcnt(0)" ::: "memory");   // own h stores done
    __syncthreads();                                    // all waves' stores done
    if (tid == 0) st4coh(bar + (size_t)(g*32 + s), (unsigned)(t + 1));
    {  // prefetch xp(t+1) in the post-flag slack (plain loads)
      const ushort* p = xpb + (size_t)(t + 1)*B_*NG;
      #pragma unroll
      for (int q = 0; q < 4; ++q)
        #pragma unroll
        for (int j = 0; j < 3; ++j)
          xq[q*3+j] = p[q*768 + 4*j];
    }
  }
}

__global__ __launch_bounds__(256, 1) void lstm_kernel(uint8_t* __restrict__ ws,
                                                      const float* __restrict__ bih,
                                                      const float* __restrict__ bhh) {
  __shared__ ushort whh_lds[73728];   // 144 KB: [kf 24][nt 6][64] 16B frag chunks
  __shared__ float gbuf[3264];        // 12.75 KB
  const int tid = threadIdx.x, lane = tid & 63, w = tid >> 6;
  const int g = blockIdx.x & 7, s = blockIdx.x >> 3;
  unsigned* bar = (unsigned*)(ws + OFF_BAR);

  const uint8_t* wsrc = ws + OFF_WHPK + (size_t)s*9216*16;
  #pragma unroll
  for (int i = 0; i < 36; ++i) {
    const int cb = (w*36 + i)*64;
    gload16(wsrc + (size_t)(cb + lane)*16, (uint8_t*)whh_lds + (size_t)cb*16);
  }

  // publish XCC_ID (sc1); one-time global init barrier (system atomic)
  const unsigned xcd = __builtin_amdgcn_s_getreg((3 << 11) | 20) & 7u;  // HW_REG_XCC_ID
  if (tid == 0) {
    st4coh(bar + 4096 + blockIdx.x, xcd);
    asm volatile("s_waitcnt vmcnt(0)" ::: "memory");
    __hip_atomic_fetch_add(bar + 5120, 1u, __ATOMIC_RELAXED, __HIP_MEMORY_SCOPE_SYSTEM);
    while (__hip_atomic_load(bar + 5120, __ATOMIC_RELAXED, __HIP_MEMORY_SCOPE_SYSTEM) < 256u)
      __builtin_amdgcn_s_sleep(2);
  }
  __syncthreads();
  const int pl = (lane < 32) ? lane : 31;
  const unsigned oxcc = ld4coh(bar + 4096 + g + 8*pl);   // peers of my group
  const bool local = __all((int)(oxcc == xcd));

  asm volatile("s_waitcnt vmcnt(0) lgkmcnt(0)" ::: "memory");
  __syncthreads();                                 // whh_lds fully staged

  if (local) run_loop<false>(ws, whh_lds, gbuf, bih, bhh, tid, g, s);
  else       run_loop<true >(ws, whh_lds, gbuf, bih, bhh, tid, g, s);
}

// ---------------- phase D: out = h_T @ W_fc^T + b_fc ----------------
__global__ __launch_bounds__(64) void fc_kernel(const uint8_t* __restrict__ ws,
                                                const float* __restrict__ wfc,
                                                const float* __restrict__ bfc,
                                                float* __restrict__ out) {
  const float* hT = (const float*)(ws + OFF_HT);
  const int b = blockIdx.x;
  const int lane = threadIdx.x;
  const float* hr = hT + (size_t)b*H_;
  float hv[12];
  #pragma unroll
  for (int i = 0; i < 12; ++i) hv[i] = hr[lane + i*64];
  for (int o = 0; o < OUT_; ++o) {
    const float* wr = wfc + (size_t)o*H_;
    float sum = 0.f;
    #pragma unroll
    for (int i = 0; i < 12; ++i) sum += hv[i] * wr[lane + i*64];
    #pragma unroll
    for (int off = 32; off; off >>= 1) sum += __shfl_xor(sum, off);
    if (lane == 0) out[(size_t)b*OUT_ + o] = sum + bfc[o];
  }
}

extern "C" void kernel_launch(void* const* d_in, const int* in_sizes, int n_in,
                              void* d_out, int out_size, void* d_ws, size_t ws_size,
                              hipStream_t stream) {
  const float* x   = (const float*)d_in[0];
  const float* wih = (const float*)d_in[1];
  const float* whh = (const float*)d_in[2];
  const float* bih = (const float*)d_in[3];
  const float* bhh = (const float*)d_in[4];
  const float* wfc = (const float*)d_in[5];
  const float* bfc = (const float*)d_in[6];
  uint8_t* ws = (uint8_t*)d_ws;
  float* out = (float*)d_out;

  prep_kernel<<<dim3(2048), dim3(256), 0, stream>>>(x, wih, whh, ws);
  xproj_kernel<<<dim3(256*24), dim3(256), 0, stream>>>(ws);
  lstm_kernel<<<dim3(256), dim3(256), 0, stream>>>(ws, bih, bhh);
  fc_kernel<<<dim3(256), dim3(64), 0, stream>>>(ws, wfc, bfc, out);
}